// Round 1
// baseline (364.971 us; speedup 1.0000x reference)
//
#include <hip/hip_runtime.h>
#include <math.h>

#define HW 128
#define CCH 64          // C
#define TILE 16
#define COG 32          // output channels per block
#define CHUNK 8         // input channels staged per LDS round
#define LSTR 20         // padded LDS row stride for 18-wide halo tile

// ---------------- splat: voxels -> heatmap / heatmap_feat via atomic max ----
__global__ void splat_kernel(const int* __restrict__ rcoors,
                             const float* __restrict__ rcs,
                             const float* __restrict__ gamma_p,
                             float* __restrict__ Hm, float* __restrict__ Fm,
                             int N, int B) {
    int n = blockIdx.x;
    if (n >= N) return;
    int b  = rcoors[n * 4 + 0];
    int yi = rcoors[n * 4 + 2];
    int xi = rcoors[n * 4 + 3];
    if ((unsigned)b >= (unsigned)B) return;
    float tr = fmaxf(rcs[n], 0.0f);
    float gamma = gamma_p[0];
    float r = floorf(gamma * tr + 1.0f);
    float sigma = (2.0f * r + 1.0f) * (1.0f / 6.0f);
    float inv2s2 = 1.0f / (2.0f * sigma * sigma);
    int R = (int)r;
    int W = 2 * R + 1;
    int tot = W * W;
    float y = (float)yi, x = (float)xi;
    for (int cell = threadIdx.x; cell < tot; cell += blockDim.x) {
        int cy = cell / W;
        int cx = cell - cy * W;
        int iy = yi - R + cy;
        int ix = xi - R + cx;
        if ((unsigned)iy >= HW || (unsigned)ix >= HW) continue;
        float dy = (float)iy - y, dx = (float)ix - x;
        float g = expf(-(dy * dy + dx * dx) * inv2s2);
        if (g < 1.1920929e-7f) continue;  // reference: g < f32 eps -> 0
        int idx = (b * HW + iy) * HW + ix;
        atomicMax((int*)&Hm[idx], __float_as_int(g));
        float gf = g * tr;
        if (gf > 0.0f) atomicMax((int*)&Fm[idx], __float_as_int(gf));
    }
}

// ---------------- fold: contract comp_w[:,64:128] with att_w / att_b --------
__global__ void fold_kernel(const float* __restrict__ comp_w,
                            const float* __restrict__ att_w,
                            const float* __restrict__ att_b,
                            float* __restrict__ wH, float* __restrict__ wF,
                            float* __restrict__ wB) {
    int tid = blockIdx.x * blockDim.x + threadIdx.x;
    if (tid >= CCH * 9) return;
    int co = tid / 9, t = tid - co * 9;
    float sH = 0.f, sF = 0.f, sB = 0.f;
    for (int c2 = 0; c2 < CCH; ++c2) {
        float w = comp_w[((size_t)co * (2 * CCH) + (CCH + c2)) * 9 + t];
        sH += w * att_w[c2 * 2 + 0];
        sF += w * att_w[c2 * 2 + 1];
        sB += w * att_b[c2];
    }
    wH[tid] = sH; wF[tid] = sF; wB[tid] = sB;
}

// ---------------- fused 3x3 conv over 66 effective input channels -----------
__global__ __launch_bounds__(256, 2)
void conv_kernel(const float* __restrict__ middle,
                 const float* __restrict__ Hm, const float* __restrict__ Fm,
                 const float* __restrict__ comp_w, const float* __restrict__ comp_b,
                 const float* __restrict__ wH, const float* __restrict__ wF,
                 const float* __restrict__ wB, float* __restrict__ out) {
    int blk = blockIdx.x;
    int bx = blk & 7, by = (blk >> 3) & 7, b = blk >> 6;
    int coBase = blockIdx.y * COG;
    int tid = threadIdx.x;
    int tx = tid & 15, ty = tid >> 4;
    int i = by * TILE + ty, j = bx * TILE + tx;
    int i0 = by * TILE - 1, j0 = bx * TILE - 1;

    __shared__ float lds[CHUNK][18 * LSTR];

    float acc[COG];
#pragma unroll
    for (int co = 0; co < COG; ++co) acc[co] = 0.0f;

    const float* base_mid = middle + (size_t)b * CCH * HW * HW;

    for (int chunk = 0; chunk < CCH / CHUNK; ++chunk) {
        // cooperative halo-tile load: CHUNK planes of 18x18 (zero-padded)
        for (int idx = tid; idx < CHUNK * 324; idx += 256) {
            int p = idx / 324;
            int rem = idx - p * 324;
            int rr = rem / 18;
            int cc = rem - rr * 18;
            int gi = i0 + rr, gj = j0 + cc;
            float v = 0.0f;
            if ((unsigned)gi < HW && (unsigned)gj < HW)
                v = base_mid[(size_t)(chunk * CHUNK + p) * HW * HW + gi * HW + gj];
            lds[p][rr * LSTR + cc] = v;
        }
        __syncthreads();

        for (int c = 0; c < CHUNK; ++c) {
            int ci = chunk * CHUNK + c;
            float nb[9];
#pragma unroll
            for (int dy = 0; dy < 3; ++dy)
#pragma unroll
                for (int dx = 0; dx < 3; ++dx)
                    nb[dy * 3 + dx] = lds[c][(ty + dy) * LSTR + (tx + dx)];
            // weights are block-uniform -> scalar loads
            const float* w0 = comp_w + ((size_t)coBase * (2 * CCH) + ci) * 9;
#pragma unroll
            for (int co = 0; co < COG; ++co) {
                const float* wc = w0 + (size_t)co * (2 * CCH) * 9;
#pragma unroll
                for (int t = 0; t < 9; ++t)
                    acc[co] = fmaf(wc[t], nb[t], acc[co]);
            }
        }
        __syncthreads();
    }

    // virtual channels: H, F, validity(ones) with folded weights wH/wF/wB
    {
        const float* baseH = Hm + (size_t)b * HW * HW;
        const float* baseF = Fm + (size_t)b * HW * HW;
        for (int idx = tid; idx < 3 * 324; idx += 256) {
            int p = idx / 324;
            int rem = idx - p * 324;
            int rr = rem / 18;
            int cc = rem - rr * 18;
            int gi = i0 + rr, gj = j0 + cc;
            bool in = ((unsigned)gi < HW) && ((unsigned)gj < HW);
            float v;
            if (p == 0)      v = in ? baseH[gi * HW + gj] : 0.0f;
            else if (p == 1) v = in ? baseF[gi * HW + gj] : 0.0f;
            else             v = in ? 1.0f : 0.0f;
            lds[p][rr * LSTR + cc] = v;
        }
        __syncthreads();
        float nbH[9], nbF[9], nbV[9];
#pragma unroll
        for (int dy = 0; dy < 3; ++dy)
#pragma unroll
            for (int dx = 0; dx < 3; ++dx) {
                nbH[dy * 3 + dx] = lds[0][(ty + dy) * LSTR + (tx + dx)];
                nbF[dy * 3 + dx] = lds[1][(ty + dy) * LSTR + (tx + dx)];
                nbV[dy * 3 + dx] = lds[2][(ty + dy) * LSTR + (tx + dx)];
            }
#pragma unroll
        for (int co = 0; co < COG; ++co) {
            int cog = coBase + co;
#pragma unroll
            for (int t = 0; t < 9; ++t) {
                acc[co] = fmaf(wH[cog * 9 + t], nbH[t], acc[co]);
                acc[co] = fmaf(wF[cog * 9 + t], nbF[t], acc[co]);
                acc[co] = fmaf(wB[cog * 9 + t], nbV[t], acc[co]);
            }
        }
    }

#pragma unroll
    for (int co = 0; co < COG; ++co) {
        int cog = coBase + co;
        out[(((size_t)b * CCH + cog) * HW + i) * HW + j] = acc[co] + comp_b[cog];
    }
}

extern "C" void kernel_launch(void* const* d_in, const int* in_sizes, int n_in,
                              void* d_out, int out_size, void* d_ws, size_t ws_size,
                              hipStream_t stream) {
    const float* middle  = (const float*)d_in[0];
    // d_in[1] voxels_feat_radar: unused by the reference
    const int*   rcoors  = (const int*)d_in[2];
    // d_in[3] batch_size scalar: derived from sizes instead
    const float* rcs     = (const float*)d_in[4];
    const float* gamma   = (const float*)d_in[5];
    const float* att_w   = (const float*)d_in[6];
    const float* att_b   = (const float*)d_in[7];
    const float* comp_w  = (const float*)d_in[8];
    const float* comp_b  = (const float*)d_in[9];
    float* out = (float*)d_out;

    int B = in_sizes[0] / (CCH * HW * HW);
    int N = in_sizes[4];

    float* ws = (float*)d_ws;
    float* Hm = ws;
    float* Fm = Hm + (size_t)B * HW * HW;
    float* wH = Fm + (size_t)B * HW * HW;
    float* wF = wH + CCH * 9;
    float* wB = wF + CCH * 9;

    hipMemsetAsync(Hm, 0, (size_t)2 * B * HW * HW * sizeof(float), stream);
    fold_kernel<<<dim3((CCH * 9 + 255) / 256), 256, 0, stream>>>(comp_w, att_w, att_b, wH, wF, wB);
    splat_kernel<<<dim3(N), 64, 0, stream>>>(rcoors, rcs, gamma, Hm, Fm, N, B);
    conv_kernel<<<dim3(B * 64, 2), 256, 0, stream>>>(middle, Hm, Fm, comp_w, comp_b, wH, wF, wB, out);
}

// Round 2
// 120.924 us; speedup vs baseline: 3.0182x; 3.0182x over previous
//
#include <hip/hip_runtime.h>
#include <math.h>

#define HW 128
#define CCH 64

typedef unsigned short u16;
typedef __attribute__((ext_vector_type(8))) short bf16x8;
typedef __attribute__((ext_vector_type(4))) float f32x4;

static __device__ __forceinline__ u16 f2bf(float x) {
    unsigned int u = __float_as_uint(x);
    unsigned int r = (u + 0x7FFFu + ((u >> 16) & 1u)) >> 16;   // RNE
    return (u16)r;
}

// ---------------- splat: voxels -> heatmap / heatmap_feat via atomic max ----
__global__ void splat_kernel(const int* __restrict__ rcoors,
                             const float* __restrict__ rcs,
                             const float* __restrict__ gamma_p,
                             float* __restrict__ Hm, float* __restrict__ Fm,
                             int N, int B) {
    int n = blockIdx.x;
    if (n >= N) return;
    int b  = rcoors[n * 4 + 0];
    int yi = rcoors[n * 4 + 2];
    int xi = rcoors[n * 4 + 3];
    if ((unsigned)b >= (unsigned)B) return;
    float tr = fmaxf(rcs[n], 0.0f);
    float gamma = gamma_p[0];
    float r = floorf(gamma * tr + 1.0f);
    float sigma = (2.0f * r + 1.0f) * (1.0f / 6.0f);
    float inv2s2 = 1.0f / (2.0f * sigma * sigma);
    int R = (int)r;
    int W = 2 * R + 1;
    int tot = W * W;
    float y = (float)yi, x = (float)xi;
    for (int cell = threadIdx.x; cell < tot; cell += blockDim.x) {
        int cy = cell / W;
        int cx = cell - cy * W;
        int iy = yi - R + cy;
        int ix = xi - R + cx;
        if ((unsigned)iy >= HW || (unsigned)ix >= HW) continue;
        float dy = (float)iy - y, dx = (float)ix - x;
        float g = expf(-(dy * dy + dx * dx) * inv2s2);
        if (g < 1.1920929e-7f) continue;  // reference: g < f32 eps -> 0
        int idx = (b * HW + iy) * HW + ix;
        atomicMax((int*)&Hm[idx], __float_as_int(g));
        float gf = g * tr;
        if (gf > 0.0f) atomicMax((int*)&Fm[idx], __float_as_int(gf));
    }
}

// ---------------- fold: contract comp_w[:,64:128] with att_w / att_b --------
__global__ void fold_kernel(const float* __restrict__ comp_w,
                            const float* __restrict__ att_w,
                            const float* __restrict__ att_b,
                            float* __restrict__ wH, float* __restrict__ wF,
                            float* __restrict__ wB) {
    int tid = blockIdx.x * blockDim.x + threadIdx.x;
    if (tid >= CCH * 9) return;
    int co = tid / 9, t = tid - co * 9;
    float sH = 0.f, sF = 0.f, sB = 0.f;
    for (int c2 = 0; c2 < CCH; ++c2) {
        float w = comp_w[((size_t)co * (2 * CCH) + (CCH + c2)) * 9 + t];
        sH += w * att_w[c2 * 2 + 0];
        sF += w * att_w[c2 * 2 + 1];
        sB += w * att_b[c2];
    }
    wH[tid] = sH; wF[tid] = sF; wB[tid] = sB;
}

// ---------------- pack weights into bf16 GEMM A matrix Wp[64][672] ----------
// K-enum: k = oct*8 + j; oct < 81: t = oct/9, ci = (oct%9)*8 + j
//   ci<64: comp_w lidar half; 64:wH 65:wF 66:wB(validity); 67..71: 0
// oct 81..83: zero pad (B side reads garbage, A zero kills it)
__global__ void packw_kernel(const float* __restrict__ comp_w,
                             const float* __restrict__ wH,
                             const float* __restrict__ wF,
                             const float* __restrict__ wB,
                             u16* __restrict__ Wp) {
    int idx = blockIdx.x * 256 + threadIdx.x;
    if (idx >= 64 * 672) return;
    int co = idx / 672, k = idx - co * 672;
    int oct = k >> 3, j = k & 7;
    u16 v = 0;
    if (oct < 81) {
        int t = oct / 9, o = oct - t * 9;
        int ci = o * 8 + j;
        float w = 0.0f;
        if (ci < 64)       w = comp_w[((size_t)co * 128 + ci) * 9 + t];
        else if (ci == 64) w = wH[co * 9 + t];
        else if (ci == 65) w = wF[co * 9 + t];
        else if (ci == 66) w = wB[co * 9 + t];
        v = f2bf(w);
    }
    Wp[idx] = v;
}

// ---------------- transpose middle NCHW f32 -> Xg NHWC bf16 -----------------
__global__ void xpose_kernel(const float* __restrict__ middle,
                             u16* __restrict__ Xg) {
    int y = blockIdx.x, b = blockIdx.y;
    int tid = threadIdx.x;
    __shared__ u16 T[128 * 72];
    for (int it = 0; it < 32; ++it) {
        int idx = it * 256 + tid;
        int ci = idx >> 7, x = idx & 127;
        float v = middle[(((size_t)b * 64 + ci) * HW + y) * HW + x];
        T[x * 72 + ci] = f2bf(v);
    }
    __syncthreads();
    u16* dst = Xg + ((size_t)(b * HW + y) * HW) * 64;
    for (int it = 0; it < 8; ++it) {
        int idx = it * 256 + tid;          // uint2 units (4 ushorts)
        int x = idx >> 4, c4 = idx & 15;
        uint2 v = *(const uint2*)(T + x * 72 + c4 * 4);
        *(uint2*)(dst + x * 64 + c4 * 4) = v;
    }
}

// ---------------- MFMA conv: 16x16 px tile x 64 co per block ----------------
__global__ __launch_bounds__(256)
void conv_kernel(const u16* __restrict__ Xg,
                 const float* __restrict__ Hm, const float* __restrict__ Fm,
                 const u16* __restrict__ Wp, const float* __restrict__ comp_b,
                 float* __restrict__ out) {
    const int bx = blockIdx.x, by = blockIdx.y, b = blockIdx.z;
    const int tid = threadIdx.x;
    const int wave = tid >> 6, lane = tid & 63;
    const int col = lane & 15, quad = lane >> 4;
    const int i0 = by * 16 - 1, j0 = bx * 16 - 1;   // halo origin

    __shared__ u16 Xs[18 * 18 * 72];                // 46656 B

    // ---- stage halo tile: [rr][cc][72]: 64 lidar bf16 + H + F + ones + pad
    {
        const u16* XgB = Xg + (size_t)b * HW * HW * 64;
        const float* HmB = Hm + b * HW * HW;
        const float* FmB = Fm + b * HW * HW;
        for (int u = tid; u < 324 * 9; u += 256) {
            int site = u / 9, slot = u - site * 9;
            int rr = site / 18, cc = site - rr * 18;
            int gi = i0 + rr, gj = j0 + cc;
            bool in = ((unsigned)gi < HW) && ((unsigned)gj < HW);
            uint4 v = make_uint4(0u, 0u, 0u, 0u);
            if (slot < 8) {
                if (in) v = *(const uint4*)(XgB + ((gi * HW + gj) * 64 + slot * 8));
            } else {
                if (in) {
                    int p = gi * HW + gj;
                    u16 hb = f2bf(HmB[p]);
                    u16 fb = f2bf(FmB[p]);
                    v.x = (unsigned)hb | ((unsigned)fb << 16);
                    v.y = 0x3F80u;   // ones(validity) bf16 1.0 | 0
                }
            }
            *(uint4*)(Xs + site * 72 + slot * 8) = v;
        }
    }
    __syncthreads();

    // ---- K-loop: 21 chunks of 32, mfma 16x16x32 bf16, 4 msubs x 4 nsubs ----
    f32x4 acc[4][4];
#pragma unroll
    for (int m = 0; m < 4; ++m)
#pragma unroll
        for (int n = 0; n < 4; ++n) acc[m][n] = (f32x4){0.f, 0.f, 0.f, 0.f};

#pragma unroll
    for (int c = 0; c < 21; ++c) {
        bf16x8 af[4];
#pragma unroll
        for (int m = 0; m < 4; ++m)
            af[m] = *(const bf16x8*)(Wp + (m * 16 + col) * 672 + c * 32 + quad * 8);

        int oct = c * 4 + quad;
        if (oct > 80) oct = 80;            // A is zero there; any valid B addr ok
        int t  = oct / 9;
        int o  = oct - t * 9;
        int dy = t / 3, dx = t - dy * 3;
        int base = ((wave * 4 + dy) * 18 + (col + dx)) * 72 + o * 8;

        bf16x8 bfr[4];
#pragma unroll
        for (int n = 0; n < 4; ++n)
            bfr[n] = *(const bf16x8*)(Xs + base + n * (18 * 72));

#pragma unroll
        for (int m = 0; m < 4; ++m)
#pragma unroll
            for (int n = 0; n < 4; ++n)
                acc[m][n] = __builtin_amdgcn_mfma_f32_16x16x32_bf16(af[m], bfr[n], acc[m][n], 0, 0, 0);
    }

    // ---- epilogue: D row = quad*4 + reg (co within msub tile), col = pixel x
#pragma unroll
    for (int m = 0; m < 4; ++m) {
        int co0 = m * 16 + quad * 4;
#pragma unroll
        for (int n = 0; n < 4; ++n) {
            int i = by * 16 + wave * 4 + n;
            int j = bx * 16 + col;
            float* o0 = out + (((size_t)(b * 64 + co0) * HW + i) * HW + j);
#pragma unroll
            for (int r = 0; r < 4; ++r)
                o0[(size_t)r * HW * HW] = acc[m][n][r] + comp_b[co0 + r];
        }
    }
}

extern "C" void kernel_launch(void* const* d_in, const int* in_sizes, int n_in,
                              void* d_out, int out_size, void* d_ws, size_t ws_size,
                              hipStream_t stream) {
    const float* middle  = (const float*)d_in[0];
    const int*   rcoors  = (const int*)d_in[2];
    const float* rcs     = (const float*)d_in[4];
    const float* gamma   = (const float*)d_in[5];
    const float* att_w   = (const float*)d_in[6];
    const float* att_b   = (const float*)d_in[7];
    const float* comp_w  = (const float*)d_in[8];
    const float* comp_b  = (const float*)d_in[9];
    float* out = (float*)d_out;

    int B = in_sizes[0] / (CCH * HW * HW);
    int N = in_sizes[4];

    // workspace layout (floats unless noted)
    float* Hm = (float*)d_ws;                       // B*16384
    float* Fm = Hm + (size_t)B * HW * HW;
    float* wH = Fm + (size_t)B * HW * HW;           // 576
    float* wF = wH + CCH * 9;
    float* wB = wF + CCH * 9;
    u16*   Wp = (u16*)(wB + CCH * 9);               // 64*672 bf16
    u16*   Xg = Wp + 64 * 672;                      // B*128*128*64 bf16

    hipMemsetAsync(Hm, 0, (size_t)2 * B * HW * HW * sizeof(float), stream);
    fold_kernel<<<dim3((CCH * 9 + 255) / 256), 256, 0, stream>>>(comp_w, att_w, att_b, wH, wF, wB);
    packw_kernel<<<dim3((64 * 672 + 255) / 256), 256, 0, stream>>>(comp_w, wH, wF, wB, Wp);
    splat_kernel<<<dim3(N), 64, 0, stream>>>(rcoors, rcs, gamma, Hm, Fm, N, B);
    xpose_kernel<<<dim3(HW, B), 256, 0, stream>>>(middle, Xg);
    conv_kernel<<<dim3(8, 8, B), 256, 0, stream>>>(Xg, Hm, Fm, Wp, comp_b, out);
}